// Round 2
// baseline (607.351 us; speedup 1.0000x reference)
//
#include <hip/hip_runtime.h>
#include <hip/hip_bf16.h>

typedef __hip_bfloat16 bf16;
typedef __attribute__((ext_vector_type(8))) short bf16x8;
typedef __attribute__((ext_vector_type(4))) float f32x4;

constexpr int NB  = 4;     // batch
constexpr int NH  = 12;    // heads
constexpr int SEQ = 1024;  // T
constexpr int HD  = 64;    // per-head dim D
constexpr int DM  = 768;   // input dim DIN = NH*HD

__device__ __forceinline__ bf16x8 ld8(const bf16* p){ return *(const bf16x8*)p; }
__device__ __forceinline__ f32x4 mfma16(bf16x8 a, bf16x8 b, f32x4 c){
  return __builtin_amdgcn_mfma_f32_16x16x32_bf16(a, b, c, 0, 0, 0);
}
union U8 { bf16x8 v; bf16 h[8]; };

// 8 consecutive fp32 -> bf16 hi + residual lo fragments
__device__ __forceinline__ void cvt_hl8(const float* p, bf16x8& hi, bf16x8& lo){
  f32x4 a = *(const f32x4*)p, b = *(const f32x4*)(p + 4);
  U8 uh, ul;
  #pragma unroll
  for (int j = 0; j < 4; j++){
    float v = a[j]; bf16 h = __float2bfloat16(v);
    uh.h[j] = h; ul.h[j] = __float2bfloat16(v - __bfloat162float(h));
  }
  #pragma unroll
  for (int j = 0; j < 4; j++){
    float v = b[j]; bf16 h = __float2bfloat16(v);
    uh.h[4+j] = h; ul.h[4+j] = __float2bfloat16(v - __bfloat162float(h));
  }
  hi = uh.v; lo = ul.v;
}
// 8 consecutive fp32 -> bf16 fragment (round-to-nearest)
__device__ __forceinline__ bf16x8 cvt8(const float* p){
  f32x4 a = *(const f32x4*)p, b = *(const f32x4*)(p + 4);
  U8 u;
  #pragma unroll
  for (int j = 0; j < 4; j++){ u.h[j] = __float2bfloat16(a[j]); u.h[4+j] = __float2bfloat16(b[j]); }
  return u.v;
}

// ---------- weight prep: transpose fp32 W[h][d][e] -> bf16 WT[h][e][d] (hi/lo for Q,K) ----------
__global__ void wprep(const float* __restrict__ Wq, const float* __restrict__ Wk,
                      const float* __restrict__ Wv, const float* __restrict__ Wo,
                      bf16* __restrict__ WqTh, bf16* __restrict__ WqTl,
                      bf16* __restrict__ WkTh, bf16* __restrict__ WkTl,
                      bf16* __restrict__ WvT,  bf16* __restrict__ WoT){
  const int z = blockIdx.y;
  const float* src; bf16 *dh, *dl; int total;
  if      (z == 0){ src = Wq; dh = WqTh; dl = WqTl; total = NH*DM*HD; }
  else if (z == 1){ src = Wk; dh = WkTh; dl = WkTl; total = NH*DM*HD; }
  else if (z == 2){ src = Wv; dh = WvT;  dl = nullptr; total = NH*DM*HD; }
  else            { src = Wo; dh = WoT;  dl = nullptr; total = DM*HD;   }
  int idx = blockIdx.x*256 + threadIdx.x;
  if (idx >= total) return;
  int d   = idx % DM;
  int tmp = idx / DM;
  int e   = tmp % HD;
  int h   = tmp / HD;
  float v = src[((size_t)h*DM + d)*HD + e];
  bf16 hi = __float2bfloat16(v);
  dh[idx] = hi;
  if (dl) dl[idx] = __float2bfloat16(v - __bfloat162float(hi));
}

// ---------- QKV projection ----------
// z=0: Q (hi/lo), z=1: K (hi/lo)  layout [NB*NH][SEQ][HD]
// z=2: V (bf16)                    layout [NB*NH][HD][SEQ]
__global__ __launch_bounds__(256) void kproj(const float* __restrict__ x,
    const bf16* __restrict__ WqTh, const bf16* __restrict__ WqTl,
    const bf16* __restrict__ WkTh, const bf16* __restrict__ WkTl,
    const bf16* __restrict__ WvT,
    bf16* __restrict__ Qhi, bf16* __restrict__ Qlo,
    bf16* __restrict__ Khi, bf16* __restrict__ Klo, bf16* __restrict__ Vt){
  const int lane = threadIdx.x & 63, w = threadIdx.x >> 6;
  const int quad = lane >> 4, lc = lane & 15;
  const int bx = blockIdx.x;
  const int nh = blockIdx.y, n = nh / NH, h = nh % NH;
  const int z = blockIdx.z;
  f32x4 acc[4] = {};
  if (z < 2){
    const bf16* WTh = (z == 0) ? WqTh : WkTh;
    const bf16* WTl = (z == 0) ? WqTl : WkTl;
    const float* xr = x + ((size_t)n*SEQ + bx*64 + w*16 + lc)*DM;   // A row m=lc
    const bf16* wbh = WTh + (size_t)h*HD*DM;
    const bf16* wbl = WTl + (size_t)h*HD*DM;
    for (int d0 = 0; d0 < DM; d0 += 32){
      bf16x8 ah, al;
      cvt_hl8(xr + d0 + quad*8, ah, al);
      #pragma unroll
      for (int ct = 0; ct < 4; ct++){
        size_t ro = (size_t)(ct*16 + lc)*DM + d0 + quad*8;
        bf16x8 bh = ld8(wbh + ro);
        bf16x8 bl = ld8(wbl + ro);
        acc[ct] = mfma16(ah, bh, acc[ct]);
        acc[ct] = mfma16(ah, bl, acc[ct]);
        acc[ct] = mfma16(al, bh, acc[ct]);
      }
    }
    bf16* Phi = (z == 0) ? Qhi : Khi;
    bf16* Plo = (z == 0) ? Qlo : Klo;
    #pragma unroll
    for (int ct = 0; ct < 4; ct++){
      #pragma unroll
      for (int i = 0; i < 4; i++){
        int t = bx*64 + w*16 + quad*4 + i;
        size_t o = ((size_t)nh*SEQ + t)*HD + ct*16 + lc;
        float v = acc[ct][i];
        bf16 hi = __float2bfloat16(v);
        Phi[o] = hi;
        Plo[o] = __float2bfloat16(v - __bfloat162float(hi));
      }
    }
  } else {
    // D[m=e][n=t] = sum_d WvT[e][d] * x[t][d]
    const bf16* wr = WvT + ((size_t)h*HD + w*16 + lc)*DM;
    for (int d0 = 0; d0 < DM; d0 += 32){
      bf16x8 a = ld8(wr + d0 + quad*8);
      #pragma unroll
      for (int ct = 0; ct < 4; ct++){
        bf16x8 b = cvt8(x + ((size_t)n*SEQ + bx*64 + ct*16 + lc)*DM + d0 + quad*8);
        acc[ct] = mfma16(a, b, acc[ct]);
      }
    }
    #pragma unroll
    for (int ct = 0; ct < 4; ct++){
      #pragma unroll
      for (int i = 0; i < 4; i++){
        int e = w*16 + quad*4 + i;
        int t = bx*64 + ct*16 + lc;
        Vt[((size_t)nh*HD + e)*SEQ + t] = __float2bfloat16(acc[ct][i]);
      }
    }
  }
}

// ---------- scores + mask + softmax -> attn (fp32, part of d_out) ----------
// block: 16 rows x 1024 cols; wave w owns cols [256w, 256w+256); S in registers
__global__ __launch_bounds__(256) void kattn(const bf16* __restrict__ Qhi, const bf16* __restrict__ Qlo,
                                             const bf16* __restrict__ Khi, const bf16* __restrict__ Klo,
                                             float* __restrict__ attn){
  const int lane = threadIdx.x & 63, w = threadIdx.x >> 6;
  const int quad = lane >> 4, lc = lane & 15;
  const int t0 = blockIdx.x * 16;
  const int nh = blockIdx.y;
  const size_t base = (size_t)nh * SEQ * HD;
  const float NEGINF = -__builtin_inff();

  f32x4 acc[16] = {};
  const bf16* qh = Qhi + base + (size_t)(t0 + lc)*HD;
  const bf16* ql = Qlo + base + (size_t)(t0 + lc)*HD;
  bf16x8 ah0 = ld8(qh + quad*8), ah1 = ld8(qh + 32 + quad*8);
  bf16x8 al0 = ld8(ql + quad*8), al1 = ld8(ql + 32 + quad*8);
  const int tmax = t0 + 15;
  #pragma unroll
  for (int tl = 0; tl < 16; tl++){
    int ct = w*256 + tl*16;
    if (ct <= tmax){
      const bf16* kh = Khi + base + (size_t)(ct + lc)*HD;
      const bf16* kl = Klo + base + (size_t)(ct + lc)*HD;
      bf16x8 bh0 = ld8(kh + quad*8), bh1 = ld8(kh + 32 + quad*8);
      bf16x8 bl0 = ld8(kl + quad*8), bl1 = ld8(kl + 32 + quad*8);
      acc[tl] = mfma16(ah0, bh0, acc[tl]);
      acc[tl] = mfma16(ah1, bh1, acc[tl]);
      acc[tl] = mfma16(ah0, bl0, acc[tl]);
      acc[tl] = mfma16(ah1, bl1, acc[tl]);
      acc[tl] = mfma16(al0, bh0, acc[tl]);
      acc[tl] = mfma16(al1, bh1, acc[tl]);
    }
  }

  // wave-local row max (masked; faithful "==0 -> -inf" quirk)
  float mx[4] = {NEGINF, NEGINF, NEGINF, NEGINF};
  #pragma unroll
  for (int tl = 0; tl < 16; tl++){
    int col = w*256 + tl*16 + lc;
    #pragma unroll
    for (int i = 0; i < 4; i++){
      int r = t0 + quad*4 + i;
      float v = acc[tl][i];
      if (col <= r && v != 0.0f) mx[i] = fmaxf(mx[i], v);
    }
  }
  #pragma unroll
  for (int off = 8; off; off >>= 1){
    #pragma unroll
    for (int i = 0; i < 4; i++) mx[i] = fmaxf(mx[i], __shfl_xor(mx[i], off, 16));
  }
  // exp + wave-local sum
  float sm[4] = {0.f, 0.f, 0.f, 0.f};
  #pragma unroll
  for (int tl = 0; tl < 16; tl++){
    int col = w*256 + tl*16 + lc;
    #pragma unroll
    for (int i = 0; i < 4; i++){
      int r = t0 + quad*4 + i;
      float v = acc[tl][i];
      float e = (col <= r && v != 0.0f) ? __expf(v - mx[i]) : 0.0f;
      acc[tl][i] = e;
      sm[i] += e;
    }
  }
  #pragma unroll
  for (int off = 8; off; off >>= 1){
    #pragma unroll
    for (int i = 0; i < 4; i++) sm[i] += __shfl_xor(sm[i], off, 16);
  }

  __shared__ float msh[4][16], lsh[4][16];
  if (lc == 0){
    #pragma unroll
    for (int i = 0; i < 4; i++){ msh[w][quad*4 + i] = mx[i]; lsh[w][quad*4 + i] = sm[i]; }
  }
  __syncthreads();

  float scale[4];
  #pragma unroll
  for (int i = 0; i < 4; i++){
    int rl = quad*4 + i;
    float M = fmaxf(fmaxf(msh[0][rl], msh[1][rl]), fmaxf(msh[2][rl], msh[3][rl]));
    float L = 0.f;
    #pragma unroll
    for (int w2 = 0; w2 < 4; w2++) L += lsh[w2][rl] * __expf(msh[w2][rl] - M);
    scale[i] = __expf(mx[i] - M) / L;
  }
  #pragma unroll
  for (int tl = 0; tl < 16; tl++){
    #pragma unroll
    for (int i = 0; i < 4; i++){
      attn[((size_t)nh*SEQ + (t0 + quad*4 + i))*SEQ + w*256 + tl*16 + lc] = acc[tl][i] * scale[i];
    }
  }
}

// ---------- O = attn @ V  (attn fp32 -> bf16 in-register); O layout [n][t][NH*HD] ----------
__global__ __launch_bounds__(256) void kpv(const float* __restrict__ attn, const bf16* __restrict__ Vt,
                                           bf16* __restrict__ O){
  const int lane = threadIdx.x & 63, w = threadIdx.x >> 6;
  const int quad = lane >> 4, lc = lane & 15;
  const int t0 = blockIdx.x * 64;
  const int nh = blockIdx.y, n = nh / NH, h = nh % NH;
  const float* Pr = attn + ((size_t)nh*SEQ + t0 + w*16 + lc)*SEQ;
  const bf16* Vb = Vt + (size_t)nh*HD*SEQ;
  f32x4 acc[4] = {};
  const int kend = t0 + 64;               // causal: attn[t][s]=0 for s>t
  for (int s0 = 0; s0 < kend; s0 += 32){
    bf16x8 a = cvt8(Pr + s0 + quad*8);
    #pragma unroll
    for (int et = 0; et < 4; et++){
      bf16x8 b = ld8(Vb + (size_t)(et*16 + lc)*SEQ + s0 + quad*8);
      acc[et] = mfma16(a, b, acc[et]);
    }
  }
  #pragma unroll
  for (int et = 0; et < 4; et++){
    #pragma unroll
    for (int i = 0; i < 4; i++){
      O[((size_t)n*SEQ + t0 + w*16 + quad*4 + i)*DM + h*HD + et*16 + lc] = __float2bfloat16(acc[et][i]);
    }
  }
}

// ---------- out = O @ Wo + bo  (fp32 out) ----------
__global__ __launch_bounds__(256) void kout(const bf16* __restrict__ O, const bf16* __restrict__ WoT,
                                            const float* __restrict__ bo, float* __restrict__ out){
  const int lane = threadIdx.x & 63, w = threadIdx.x >> 6;
  const int quad = lane >> 4, lc = lane & 15;
  const int m0 = blockIdx.x * 64;
  const int n = m0 >> 10, tb = m0 & 1023;
  const bf16* Or = O + ((size_t)n*SEQ + tb + w*16 + lc)*DM;   // A row m=lc, contiguous k
  f32x4 acc[4] = {};
  for (int k0 = 0; k0 < DM; k0 += 32){
    bf16x8 a = ld8(Or + k0 + quad*8);
    #pragma unroll
    for (int ct = 0; ct < 4; ct++){
      bf16x8 b = ld8(WoT + (size_t)(ct*16 + lc)*DM + k0 + quad*8);
      acc[ct] = mfma16(a, b, acc[ct]);
    }
  }
  #pragma unroll
  for (int ct = 0; ct < 4; ct++){
    float bias = bo[ct*16 + lc];
    #pragma unroll
    for (int i = 0; i < 4; i++){
      out[((size_t)n*SEQ + tb + w*16 + quad*4 + i)*HD + ct*16 + lc] = acc[ct][i] + bias;
    }
  }
}

extern "C" void kernel_launch(void* const* d_in, const int* in_sizes, int n_in,
                              void* d_out, int out_size, void* d_ws, size_t ws_size,
                              hipStream_t stream){
  const float* x  = (const float*)d_in[0];
  const float* Wq = (const float*)d_in[1];
  const float* Wk = (const float*)d_in[2];
  const float* Wv = (const float*)d_in[3];
  const float* Wo = (const float*)d_in[4];
  const float* bo = (const float*)d_in[5];

  float* out  = (float*)d_out;
  float* attn = out + (size_t)NB*SEQ*HD;    // tuple output: out first, then attn

  constexpr size_t SZ_WT  = (size_t)NH*HD*DM;     // 589824
  constexpr size_t SZ_WOT = (size_t)HD*DM;        // 49152
  constexpr size_t SZ_QKV = (size_t)NB*NH*SEQ*HD; // 3145728
  bf16* b = (bf16*)d_ws;
  bf16* WqTh = b;  b += SZ_WT;
  bf16* WqTl = b;  b += SZ_WT;
  bf16* WkTh = b;  b += SZ_WT;
  bf16* WkTl = b;  b += SZ_WT;
  bf16* WvT  = b;  b += SZ_WT;
  bf16* WoT  = b;  b += SZ_WOT;
  bf16* Qhi  = b;  b += SZ_QKV;
  bf16* Qlo  = b;  b += SZ_QKV;
  bf16* Khi  = b;  b += SZ_QKV;
  bf16* Klo  = b;  b += SZ_QKV;
  bf16* Vt   = b;  b += SZ_QKV;
  bf16* O    = b;

  wprep<<<dim3((NH*DM*HD + 255)/256, 4), 256, 0, stream>>>(Wq, Wk, Wv, Wo,
                                                           WqTh, WqTl, WkTh, WkTl, WvT, WoT);
  kproj<<<dim3(SEQ/64, NB*NH, 3), 256, 0, stream>>>(x, WqTh, WqTl, WkTh, WkTl, WvT,
                                                    Qhi, Qlo, Khi, Klo, Vt);
  kattn<<<dim3(SEQ/16, NB*NH), 256, 0, stream>>>(Qhi, Qlo, Khi, Klo, attn);
  kpv<<<dim3(SEQ/64, NB*NH), 256, 0, stream>>>(attn, Vt, O);
  kout<<<dim3(NB*SEQ/64), 256, 0, stream>>>(O, WoT, bo, out);
}

// Round 3
// 379.326 us; speedup vs baseline: 1.6011x; 1.6011x over previous
//
#include <hip/hip_runtime.h>
#include <hip/hip_bf16.h>

typedef __hip_bfloat16 bf16;
typedef __attribute__((ext_vector_type(8))) short bf16x8;
typedef __attribute__((ext_vector_type(4))) float f32x4;

constexpr int NB  = 4;
constexpr int NH  = 12;
constexpr int SEQ = 1024;
constexpr int HD  = 64;
constexpr int DM  = 768;
constexpr int LDA = 40;   // padded LDS row (elems): 80 B rows -> 16B-aligned, 2-way max conflict

__device__ __forceinline__ bf16x8 ld8(const bf16* p){ return *(const bf16x8*)p; }
__device__ __forceinline__ f32x4 mfma16(bf16x8 a, bf16x8 b, f32x4 c){
  return __builtin_amdgcn_mfma_f32_16x16x32_bf16(a, b, c, 0, 0, 0);
}
union U8 { bf16x8 v; bf16 h[8]; };

// ---------------- wprep: LDS-tiled transpose, fp32 W[.][d][e] -> bf16 WT[.][e][d] ----------------
// grid: (dt=12, y=37): y<36: z=y/12 (Wq,Wk,Wv), h=y%12 ; y==36: Wo (768x64 -> 64x768)
__global__ __launch_bounds__(256) void wprep(const float* __restrict__ Wq, const float* __restrict__ Wk,
                      const float* __restrict__ Wv, const float* __restrict__ Wo,
                      bf16* __restrict__ WqTh, bf16* __restrict__ WqTl,
                      bf16* __restrict__ WkTh, bf16* __restrict__ WkTl,
                      bf16* __restrict__ WvT,  bf16* __restrict__ WoT){
  __shared__ float sT[64][65];
  const int tid = threadIdx.x;
  const int dt = blockIdx.x, y = blockIdx.y;
  const float* src; bf16* dh; bf16* dl = nullptr;
  if (y < 36){
    int z = y / 12, h = y % 12;
    src = (z==0 ? Wq : z==1 ? Wk : Wv) + (size_t)h*DM*HD;
    dh  = (z==0 ? WqTh : z==1 ? WkTh : WvT) + (size_t)h*HD*DM;
    if (z==0) dl = WqTl + (size_t)h*HD*DM;
    if (z==1) dl = WkTl + (size_t)h*HD*DM;
  } else { src = Wo; dh = WoT; }

  // coalesced read of 64(d) x 64(e) fp32 tile
  {
    int r = tid >> 2, c = (tid & 3) * 16;
    const float* sp = src + ((size_t)(dt*64 + r))*HD + c;
    f32x4 v0 = *(const f32x4*)sp, v1 = *(const f32x4*)(sp+4),
          v2 = *(const f32x4*)(sp+8), v3 = *(const f32x4*)(sp+12);
    #pragma unroll
    for (int j = 0; j < 4; j++){
      sT[r][c+j] = v0[j]; sT[r][c+4+j] = v1[j]; sT[r][c+8+j] = v2[j]; sT[r][c+12+j] = v3[j];
    }
  }
  __syncthreads();
  // transposed write: thread -> out row e, 16 consecutive d
  {
    int e = tid >> 2, co = (tid & 3) * 16;
    U8 uh0, ul0, uh1, ul1;
    #pragma unroll
    for (int j = 0; j < 8; j++){
      float v = sT[co + j][e];
      bf16 hi = __float2bfloat16(v);
      uh0.h[j] = hi; ul0.h[j] = __float2bfloat16(v - __bfloat162float(hi));
    }
    #pragma unroll
    for (int j = 0; j < 8; j++){
      float v = sT[co + 8 + j][e];
      bf16 hi = __float2bfloat16(v);
      uh1.h[j] = hi; ul1.h[j] = __float2bfloat16(v - __bfloat162float(hi));
    }
    size_t o = (size_t)e*DM + dt*64 + co;
    *(bf16x8*)(dh + o) = uh0.v; *(bf16x8*)(dh + o + 8) = uh1.v;
    if (dl){ *(bf16x8*)(dl + o) = ul0.v; *(bf16x8*)(dl + o + 8) = ul1.v; }
  }
}

// ---------------- xprep: x fp32 -> xh, xl bf16 (coalesced) ----------------
__global__ __launch_bounds__(256) void xprep(const float* __restrict__ x,
                                             bf16* __restrict__ xh, bf16* __restrict__ xl){
  size_t base = ((size_t)blockIdx.x*256 + threadIdx.x)*8;
  f32x4 a = *(const f32x4*)(x + base), b = *(const f32x4*)(x + base + 4);
  U8 uh, ul;
  #pragma unroll
  for (int j = 0; j < 4; j++){
    bf16 h0 = __float2bfloat16(a[j]);
    uh.h[j] = h0; ul.h[j] = __float2bfloat16(a[j] - __bfloat162float(h0));
    bf16 h1 = __float2bfloat16(b[j]);
    uh.h[4+j] = h1; ul.h[4+j] = __float2bfloat16(b[j] - __bfloat162float(h1));
  }
  *(bf16x8*)(xh + base) = uh.v;
  *(bf16x8*)(xl + base) = ul.v;
}

// ---------------- kproj: LDS-staged GEMM ----------------
// z=0/1: Q/K  (M=128 t-rows, N=64 e-cols, hi/lo 3-term)  out [nh][t][e] hi+lo
// z=2  : V    (A=WvT 64 e-rows, B=xh 128 t-cols)         out Vt [nh][e][t]
__global__ __launch_bounds__(256) void kproj(const bf16* __restrict__ xh, const bf16* __restrict__ xl,
    const bf16* __restrict__ WqTh, const bf16* __restrict__ WqTl,
    const bf16* __restrict__ WkTh, const bf16* __restrict__ WkTl,
    const bf16* __restrict__ WvT,
    bf16* __restrict__ Qhi, bf16* __restrict__ Qlo,
    bf16* __restrict__ Khi, bf16* __restrict__ Klo, bf16* __restrict__ Vt){
  __shared__ bf16 sA[2][128*LDA];
  __shared__ bf16 sB[2][64*LDA];
  const int tid = threadIdx.x;
  const int lane = tid & 63, w = tid >> 6;
  const int quad = lane >> 4, lc = lane & 15;
  const int mb = blockIdx.x, h = blockIdx.y, z = blockIdx.z;
  const int sr = tid >> 2;            // 0..63
  const int sc = (tid & 3) * 8;       // 0,8,16,24
  const int wm = w & 1, wn = w >> 1;

  if (z < 2){
    const bf16* Bh = (z==0 ? WqTh : WkTh) + (size_t)h*HD*DM;
    const bf16* Bl = (z==0 ? WqTl : WkTl) + (size_t)h*HD*DM;
    bf16* Ph = (z==0 ? Qhi : Khi);
    bf16* Pl = (z==0 ? Qlo : Klo);
    f32x4 acc[4][2] = {};
    bf16x8 pa0,pa1,pa2,pa3,pb0,pb1;
    auto ldchunk = [&](int kc){
      size_t col = (size_t)kc*32 + sc;
      pa0 = ld8(xh + (size_t)(mb*128 + sr)*DM + col);
      pa1 = ld8(xh + (size_t)(mb*128 + sr + 64)*DM + col);
      pa2 = ld8(xl + (size_t)(mb*128 + sr)*DM + col);
      pa3 = ld8(xl + (size_t)(mb*128 + sr + 64)*DM + col);
      pb0 = ld8(Bh + (size_t)sr*DM + col);
      pb1 = ld8(Bl + (size_t)sr*DM + col);
    };
    ldchunk(0);
    for (int kc = 0; kc < DM/32; kc++){
      *(bf16x8*)&sA[0][sr*LDA + sc] = pa0;
      *(bf16x8*)&sA[0][(sr+64)*LDA + sc] = pa1;
      *(bf16x8*)&sA[1][sr*LDA + sc] = pa2;
      *(bf16x8*)&sA[1][(sr+64)*LDA + sc] = pa3;
      *(bf16x8*)&sB[0][sr*LDA + sc] = pb0;
      *(bf16x8*)&sB[1][sr*LDA + sc] = pb1;
      __syncthreads();
      if (kc < DM/32 - 1) ldchunk(kc + 1);
      bf16x8 bh[2], bl[2];
      #pragma unroll
      for (int nt = 0; nt < 2; nt++){
        bh[nt] = *(const bf16x8*)&sB[0][(wn*32 + nt*16 + lc)*LDA + quad*8];
        bl[nt] = *(const bf16x8*)&sB[1][(wn*32 + nt*16 + lc)*LDA + quad*8];
      }
      #pragma unroll
      for (int mt = 0; mt < 4; mt++){
        bf16x8 ah = *(const bf16x8*)&sA[0][(wm*64 + mt*16 + lc)*LDA + quad*8];
        bf16x8 al = *(const bf16x8*)&sA[1][(wm*64 + mt*16 + lc)*LDA + quad*8];
        #pragma unroll
        for (int nt = 0; nt < 2; nt++){
          acc[mt][nt] = mfma16(ah, bh[nt], acc[mt][nt]);
          acc[mt][nt] = mfma16(ah, bl[nt], acc[mt][nt]);
          acc[mt][nt] = mfma16(al, bh[nt], acc[mt][nt]);
        }
      }
      __syncthreads();
    }
    #pragma unroll
    for (int mt = 0; mt < 4; mt++){
      #pragma unroll
      for (int nt = 0; nt < 2; nt++){
        #pragma unroll
        for (int i = 0; i < 4; i++){
          int tg = mb*128 + wm*64 + mt*16 + quad*4 + i;
          int e  = wn*32 + nt*16 + lc;
          int n = tg >> 10, t = tg & 1023;
          size_t o = ((size_t)(n*NH + h)*SEQ + t)*HD + e;
          float v = acc[mt][nt][i];
          bf16 hi = __float2bfloat16(v);
          Ph[o] = hi;
          Pl[o] = __float2bfloat16(v - __bfloat162float(hi));
        }
      }
    }
  } else {
    // V: A = WvT[h] (64 e-rows), B = xh (128 t-rows as B^T rows)
    const bf16* Av = WvT + (size_t)h*HD*DM;
    f32x4 acc[2][4] = {};
    bf16x8 pa0, pb0, pb1;
    auto ldchunk = [&](int kc){
      size_t col = (size_t)kc*32 + sc;
      pa0 = ld8(Av + (size_t)sr*DM + col);
      pb0 = ld8(xh + (size_t)(mb*128 + sr)*DM + col);
      pb1 = ld8(xh + (size_t)(mb*128 + sr + 64)*DM + col);
    };
    ldchunk(0);
    for (int kc = 0; kc < DM/32; kc++){
      *(bf16x8*)&sB[0][sr*LDA + sc] = pa0;
      *(bf16x8*)&sA[0][sr*LDA + sc] = pb0;
      *(bf16x8*)&sA[0][(sr+64)*LDA + sc] = pb1;
      __syncthreads();
      if (kc < DM/32 - 1) ldchunk(kc + 1);
      bf16x8 bt[4];
      #pragma unroll
      for (int nt = 0; nt < 4; nt++)
        bt[nt] = *(const bf16x8*)&sA[0][(wn*64 + nt*16 + lc)*LDA + quad*8];
      #pragma unroll
      for (int mt = 0; mt < 2; mt++){
        bf16x8 a = *(const bf16x8*)&sB[0][(wm*32 + mt*16 + lc)*LDA + quad*8];
        #pragma unroll
        for (int nt = 0; nt < 4; nt++)
          acc[mt][nt] = mfma16(a, bt[nt], acc[mt][nt]);
      }
      __syncthreads();
    }
    #pragma unroll
    for (int mt = 0; mt < 2; mt++){
      #pragma unroll
      for (int nt = 0; nt < 4; nt++){
        #pragma unroll
        for (int i = 0; i < 4; i++){
          int e  = wm*32 + mt*16 + quad*4 + i;
          int tg = mb*128 + wn*64 + nt*16 + lc;
          int n = tg >> 10, t = tg & 1023;
          Vt[((size_t)(n*NH + h)*HD + e)*SEQ + t] = __float2bfloat16(acc[mt][nt][i]);
        }
      }
    }
  }
}

// ---------------- fused scores + softmax + attn-write + PV ----------------
// block: 16 rows x 1024 cols; wave w owns score cols [256w,256w+256); then PV with P via LDS
__global__ __launch_bounds__(256) void kattn_pv(const bf16* __restrict__ Qhi, const bf16* __restrict__ Qlo,
                                                const bf16* __restrict__ Khi, const bf16* __restrict__ Klo,
                                                const bf16* __restrict__ Vt,
                                                float* __restrict__ attn, bf16* __restrict__ O){
  __shared__ bf16 sP[16][SEQ + 8];
  __shared__ float msh[4][16], lsh[4][16];
  const int lane = threadIdx.x & 63, w = threadIdx.x >> 6;
  const int quad = lane >> 4, lc = lane & 15;
  const int t0 = blockIdx.x * 16;
  const int nh = blockIdx.y;
  const size_t base = (size_t)nh * SEQ * HD;
  const float NEGINF = -__builtin_inff();

  f32x4 acc[16] = {};
  const bf16* qh = Qhi + base + (size_t)(t0 + lc)*HD;
  const bf16* ql = Qlo + base + (size_t)(t0 + lc)*HD;
  bf16x8 ah0 = ld8(qh + quad*8), ah1 = ld8(qh + 32 + quad*8);
  bf16x8 al0 = ld8(ql + quad*8), al1 = ld8(ql + 32 + quad*8);
  const int tmax = t0 + 15;
  #pragma unroll
  for (int tl = 0; tl < 16; tl++){
    int ct = w*256 + tl*16;
    if (ct <= tmax){
      const bf16* kh = Khi + base + (size_t)(ct + lc)*HD;
      const bf16* kl = Klo + base + (size_t)(ct + lc)*HD;
      bf16x8 bh0 = ld8(kh + quad*8), bh1 = ld8(kh + 32 + quad*8);
      bf16x8 bl0 = ld8(kl + quad*8), bl1 = ld8(kl + 32 + quad*8);
      acc[tl] = mfma16(ah0, bh0, acc[tl]);
      acc[tl] = mfma16(ah1, bh1, acc[tl]);
      acc[tl] = mfma16(ah0, bl0, acc[tl]);
      acc[tl] = mfma16(ah1, bl1, acc[tl]);
      acc[tl] = mfma16(al0, bh0, acc[tl]);
      acc[tl] = mfma16(al1, bh1, acc[tl]);
    }
  }

  float mx[4] = {NEGINF, NEGINF, NEGINF, NEGINF};
  #pragma unroll
  for (int tl = 0; tl < 16; tl++){
    int col = w*256 + tl*16 + lc;
    #pragma unroll
    for (int i = 0; i < 4; i++){
      int r = t0 + quad*4 + i;
      float v = acc[tl][i];
      if (col <= r && v != 0.0f) mx[i] = fmaxf(mx[i], v);
    }
  }
  #pragma unroll
  for (int off = 8; off; off >>= 1){
    #pragma unroll
    for (int i = 0; i < 4; i++) mx[i] = fmaxf(mx[i], __shfl_xor(mx[i], off, 16));
  }
  float sm[4] = {0.f, 0.f, 0.f, 0.f};
  #pragma unroll
  for (int tl = 0; tl < 16; tl++){
    int col = w*256 + tl*16 + lc;
    #pragma unroll
    for (int i = 0; i < 4; i++){
      int r = t0 + quad*4 + i;
      float v = acc[tl][i];
      float e = (col <= r && v != 0.0f) ? __expf(v - mx[i]) : 0.0f;
      acc[tl][i] = e;
      sm[i] += e;
    }
  }
  #pragma unroll
  for (int off = 8; off; off >>= 1){
    #pragma unroll
    for (int i = 0; i < 4; i++) sm[i] += __shfl_xor(sm[i], off, 16);
  }
  if (lc == 0){
    #pragma unroll
    for (int i = 0; i < 4; i++){ msh[w][quad*4 + i] = mx[i]; lsh[w][quad*4 + i] = sm[i]; }
  }
  __syncthreads();
  float scale[4];
  #pragma unroll
  for (int i = 0; i < 4; i++){
    int rl = quad*4 + i;
    float M = fmaxf(fmaxf(msh[0][rl], msh[1][rl]), fmaxf(msh[2][rl], msh[3][rl]));
    float L = 0.f;
    #pragma unroll
    for (int w2 = 0; w2 < 4; w2++) L += lsh[w2][rl] * __expf(msh[w2][rl] - M);
    scale[i] = __expf(mx[i] - M) / L;
  }
  // write attn (fp32 output) + stage P (bf16) to LDS
  #pragma unroll
  for (int tl = 0; tl < 16; tl++){
    int col = w*256 + tl*16 + lc;
    #pragma unroll
    for (int i = 0; i < 4; i++){
      int row = quad*4 + i;
      float p = acc[tl][i] * scale[i];
      attn[((size_t)nh*SEQ + (t0 + row))*SEQ + col] = p;
      sP[row][col] = __float2bfloat16(p);
    }
  }
  __syncthreads();

  // PV: wave w -> output cols [w*16, w*16+16)
  f32x4 oacc = {};
  const bf16* Vb = Vt + ((size_t)nh*HD + w*16 + lc)*SEQ;
  const int kend = t0 + 16;
  for (int s0 = 0; s0 < kend; s0 += 32){
    bf16x8 a = *(const bf16x8*)&sP[lc][s0 + quad*8];
    bf16x8 b = ld8(Vb + s0 + quad*8);
    oacc = mfma16(a, b, oacc);
  }
  const int n = nh / NH, h = nh % NH;
  #pragma unroll
  for (int i = 0; i < 4; i++){
    O[((size_t)n*SEQ + t0 + quad*4 + i)*DM + h*HD + w*16 + lc] = __float2bfloat16(oacc[i]);
  }
}

// ---------------- out = O @ Wo + bo ----------------
__global__ __launch_bounds__(256) void kout(const bf16* __restrict__ O, const bf16* __restrict__ WoT,
                                            const float* __restrict__ bo, float* __restrict__ out){
  const int lane = threadIdx.x & 63, w = threadIdx.x >> 6;
  const int quad = lane >> 4, lc = lane & 15;
  const int m0 = blockIdx.x * 64;
  const int n = m0 >> 10, tb = m0 & 1023;
  const bf16* Or = O + ((size_t)n*SEQ + tb + w*16 + lc)*DM;
  f32x4 acc[4] = {};
  for (int k0 = 0; k0 < DM; k0 += 32){
    bf16x8 a = ld8(Or + k0 + quad*8);
    #pragma unroll
    for (int ct = 0; ct < 4; ct++){
      bf16x8 b = ld8(WoT + (size_t)(ct*16 + lc)*DM + k0 + quad*8);
      acc[ct] = mfma16(a, b, acc[ct]);
    }
  }
  #pragma unroll
  for (int ct = 0; ct < 4; ct++){
    float bias = bo[ct*16 + lc];
    #pragma unroll
    for (int i = 0; i < 4; i++){
      out[((size_t)n*SEQ + tb + w*16 + quad*4 + i)*HD + ct*16 + lc] = acc[ct][i] + bias;
    }
  }
}

extern "C" void kernel_launch(void* const* d_in, const int* in_sizes, int n_in,
                              void* d_out, int out_size, void* d_ws, size_t ws_size,
                              hipStream_t stream){
  const float* x  = (const float*)d_in[0];
  const float* Wq = (const float*)d_in[1];
  const float* Wk = (const float*)d_in[2];
  const float* Wv = (const float*)d_in[3];
  const float* Wo = (const float*)d_in[4];
  const float* bo = (const float*)d_in[5];

  float* out  = (float*)d_out;
  float* attn = out + (size_t)NB*SEQ*HD;

  constexpr size_t SZ_WT  = (size_t)NH*HD*DM;
  constexpr size_t SZ_WOT = (size_t)HD*DM;
  constexpr size_t SZ_Q   = (size_t)NB*NH*SEQ*HD;   // == NB*SEQ*DM
  bf16* b = (bf16*)d_ws;
  bf16* WqTh = b;  b += SZ_WT;
  bf16* WqTl = b;  b += SZ_WT;
  bf16* WkTh = b;  b += SZ_WT;
  bf16* WkTl = b;  b += SZ_WT;
  bf16* WvT  = b;  b += SZ_WT;
  bf16* WoT  = b;  b += SZ_WOT;
  bf16* xh   = b;  b += SZ_Q;
  bf16* xl   = b;  b += SZ_Q;
  bf16* Qhi  = b;  b += SZ_Q;
  bf16* Qlo  = b;  b += SZ_Q;
  bf16* Khi  = b;  b += SZ_Q;
  bf16* Klo  = b;  b += SZ_Q;
  bf16* Vt   = b;  b += SZ_Q;
  bf16* O    = xh;   // alias: xh dead after kproj

  wprep<<<dim3(12, 37), 256, 0, stream>>>(Wq, Wk, Wv, Wo, WqTh, WqTl, WkTh, WkTl, WvT, WoT);
  xprep<<<dim3((int)(SZ_Q/(256*8))), 256, 0, stream>>>(x, xh, xl);
  kproj<<<dim3(NB*SEQ/128, NH, 3), 256, 0, stream>>>(xh, xl, WqTh, WqTl, WkTh, WkTl, WvT,
                                                     Qhi, Qlo, Khi, Klo, Vt);
  kattn_pv<<<dim3(SEQ/16, NB*NH), 256, 0, stream>>>(Qhi, Qlo, Khi, Klo, Vt, attn, O);
  kout<<<dim3(NB*SEQ/64), 256, 0, stream>>>(O, WoT, bo, out);
}

// Round 4
// 360.964 us; speedup vs baseline: 1.6826x; 1.0509x over previous
//
#include <hip/hip_runtime.h>
#include <hip/hip_bf16.h>

typedef __hip_bfloat16 bf16;
typedef __attribute__((ext_vector_type(8))) short bf16x8;
typedef __attribute__((ext_vector_type(4))) float f32x4;

constexpr int NB  = 4;
constexpr int NH  = 12;
constexpr int SEQ = 1024;
constexpr int HD  = 64;
constexpr int DM  = 768;
constexpr int LDA = 40;   // padded LDS row (elems)

__device__ __forceinline__ bf16x8 ld8(const bf16* p){ return *(const bf16x8*)p; }
__device__ __forceinline__ f32x4 mfma16(bf16x8 a, bf16x8 b, f32x4 c){
  return __builtin_amdgcn_mfma_f32_16x16x32_bf16(a, b, c, 0, 0, 0);
}
union U8 { bf16x8 v; bf16 h[8]; };

// ---------------- wprep: LDS-tiled transpose, fp32 W[.][d][e] -> bf16 WT[.][e][d] ----------------
__global__ __launch_bounds__(256) void wprep(const float* __restrict__ Wq, const float* __restrict__ Wk,
                      const float* __restrict__ Wv, const float* __restrict__ Wo,
                      bf16* __restrict__ WqTh, bf16* __restrict__ WqTl,
                      bf16* __restrict__ WkTh, bf16* __restrict__ WkTl,
                      bf16* __restrict__ WvT,  bf16* __restrict__ WoT){
  __shared__ float sT[64][65];
  const int tid = threadIdx.x;
  const int dt = blockIdx.x, y = blockIdx.y;
  const float* src; bf16* dh; bf16* dl = nullptr;
  if (y < 36){
    int z = y / 12, h = y % 12;
    src = (z==0 ? Wq : z==1 ? Wk : Wv) + (size_t)h*DM*HD;
    dh  = (z==0 ? WqTh : z==1 ? WkTh : WvT) + (size_t)h*HD*DM;
    if (z==0) dl = WqTl + (size_t)h*HD*DM;
    if (z==1) dl = WkTl + (size_t)h*HD*DM;
  } else { src = Wo; dh = WoT; }

  {
    int r = tid >> 2, c = (tid & 3) * 16;
    const float* sp = src + ((size_t)(dt*64 + r))*HD + c;
    f32x4 v0 = *(const f32x4*)sp, v1 = *(const f32x4*)(sp+4),
          v2 = *(const f32x4*)(sp+8), v3 = *(const f32x4*)(sp+12);
    #pragma unroll
    for (int j = 0; j < 4; j++){
      sT[r][c+j] = v0[j]; sT[r][c+4+j] = v1[j]; sT[r][c+8+j] = v2[j]; sT[r][c+12+j] = v3[j];
    }
  }
  __syncthreads();
  {
    int e = tid >> 2, co = (tid & 3) * 16;
    U8 uh0, ul0, uh1, ul1;
    #pragma unroll
    for (int j = 0; j < 8; j++){
      float v = sT[co + j][e];
      bf16 hi = __float2bfloat16(v);
      uh0.h[j] = hi; ul0.h[j] = __float2bfloat16(v - __bfloat162float(hi));
    }
    #pragma unroll
    for (int j = 0; j < 8; j++){
      float v = sT[co + 8 + j][e];
      bf16 hi = __float2bfloat16(v);
      uh1.h[j] = hi; ul1.h[j] = __float2bfloat16(v - __bfloat162float(hi));
    }
    size_t o = (size_t)e*DM + dt*64 + co;
    *(bf16x8*)(dh + o) = uh0.v; *(bf16x8*)(dh + o + 8) = uh1.v;
    if (dl){ *(bf16x8*)(dl + o) = ul0.v; *(bf16x8*)(dl + o + 8) = ul1.v; }
  }
}

// ---------------- xprep ----------------
__global__ __launch_bounds__(256) void xprep(const float* __restrict__ x,
                                             bf16* __restrict__ xh, bf16* __restrict__ xl){
  size_t base = ((size_t)blockIdx.x*256 + threadIdx.x)*8;
  f32x4 a = *(const f32x4*)(x + base), b = *(const f32x4*)(x + base + 4);
  U8 uh, ul;
  #pragma unroll
  for (int j = 0; j < 4; j++){
    bf16 h0 = __float2bfloat16(a[j]);
    uh.h[j] = h0; ul.h[j] = __float2bfloat16(a[j] - __bfloat162float(h0));
    bf16 h1 = __float2bfloat16(b[j]);
    uh.h[4+j] = h1; ul.h[4+j] = __float2bfloat16(b[j] - __bfloat162float(h1));
  }
  *(bf16x8*)(xh + base) = uh.v;
  *(bf16x8*)(xl + base) = ul.v;
}

// ---------------- kproj: LDS-staged GEMM ----------------
// z=0: Q AND K (share staged x tiles, hi/lo 3-term)  out [nh][t][e] hi+lo
// z=1: V (A=WvT 64 e-rows, B=xh 128 t-cols)          out Vt [nh][e][t]
__global__ __launch_bounds__(256) void kproj(const bf16* __restrict__ xh, const bf16* __restrict__ xl,
    const bf16* __restrict__ WqTh, const bf16* __restrict__ WqTl,
    const bf16* __restrict__ WkTh, const bf16* __restrict__ WkTl,
    const bf16* __restrict__ WvT,
    bf16* __restrict__ Qhi, bf16* __restrict__ Qlo,
    bf16* __restrict__ Khi, bf16* __restrict__ Klo, bf16* __restrict__ Vt){
  __shared__ bf16 sA[2][128*LDA];
  __shared__ bf16 sB[4][64*LDA];
  const int tid = threadIdx.x;
  const int lane = tid & 63, w = tid >> 6;
  const int quad = lane >> 4, lc = lane & 15;
  const int mb = blockIdx.x, h = blockIdx.y, z = blockIdx.z;
  const int sr = tid >> 2;
  const int sc = (tid & 3) * 8;
  const int wm = w & 1, wn = w >> 1;

  if (z == 0){
    const bf16* Bqh = WqTh + (size_t)h*HD*DM;
    const bf16* Bql = WqTl + (size_t)h*HD*DM;
    const bf16* Bkh = WkTh + (size_t)h*HD*DM;
    const bf16* Bkl = WkTl + (size_t)h*HD*DM;
    f32x4 aq[4][2] = {}, ak[4][2] = {};
    bf16x8 pa0,pa1,pa2,pa3,pq0,pq1,pk0,pk1;
    auto ldchunk = [&](int kc){
      size_t col = (size_t)kc*32 + sc;
      pa0 = ld8(xh + (size_t)(mb*128 + sr)*DM + col);
      pa1 = ld8(xh + (size_t)(mb*128 + sr + 64)*DM + col);
      pa2 = ld8(xl + (size_t)(mb*128 + sr)*DM + col);
      pa3 = ld8(xl + (size_t)(mb*128 + sr + 64)*DM + col);
      pq0 = ld8(Bqh + (size_t)sr*DM + col);
      pq1 = ld8(Bql + (size_t)sr*DM + col);
      pk0 = ld8(Bkh + (size_t)sr*DM + col);
      pk1 = ld8(Bkl + (size_t)sr*DM + col);
    };
    ldchunk(0);
    for (int kc = 0; kc < DM/32; kc++){
      *(bf16x8*)&sA[0][sr*LDA + sc] = pa0;
      *(bf16x8*)&sA[0][(sr+64)*LDA + sc] = pa1;
      *(bf16x8*)&sA[1][sr*LDA + sc] = pa2;
      *(bf16x8*)&sA[1][(sr+64)*LDA + sc] = pa3;
      *(bf16x8*)&sB[0][sr*LDA + sc] = pq0;
      *(bf16x8*)&sB[1][sr*LDA + sc] = pq1;
      *(bf16x8*)&sB[2][sr*LDA + sc] = pk0;
      *(bf16x8*)&sB[3][sr*LDA + sc] = pk1;
      __syncthreads();
      if (kc < DM/32 - 1) ldchunk(kc + 1);
      bf16x8 bqh[2], bql[2], bkh[2], bkl[2];
      #pragma unroll
      for (int nt = 0; nt < 2; nt++){
        int ro = (wn*32 + nt*16 + lc)*LDA + quad*8;
        bqh[nt] = *(const bf16x8*)&sB[0][ro];
        bql[nt] = *(const bf16x8*)&sB[1][ro];
        bkh[nt] = *(const bf16x8*)&sB[2][ro];
        bkl[nt] = *(const bf16x8*)&sB[3][ro];
      }
      #pragma unroll
      for (int mt = 0; mt < 4; mt++){
        bf16x8 ah = *(const bf16x8*)&sA[0][(wm*64 + mt*16 + lc)*LDA + quad*8];
        bf16x8 al = *(const bf16x8*)&sA[1][(wm*64 + mt*16 + lc)*LDA + quad*8];
        #pragma unroll
        for (int nt = 0; nt < 2; nt++){
          aq[mt][nt] = mfma16(ah, bqh[nt], aq[mt][nt]);
          aq[mt][nt] = mfma16(ah, bql[nt], aq[mt][nt]);
          aq[mt][nt] = mfma16(al, bqh[nt], aq[mt][nt]);
          ak[mt][nt] = mfma16(ah, bkh[nt], ak[mt][nt]);
          ak[mt][nt] = mfma16(ah, bkl[nt], ak[mt][nt]);
          ak[mt][nt] = mfma16(al, bkh[nt], ak[mt][nt]);
        }
      }
      __syncthreads();
    }
    #pragma unroll
    for (int mt = 0; mt < 4; mt++){
      #pragma unroll
      for (int nt = 0; nt < 2; nt++){
        #pragma unroll
        for (int i = 0; i < 4; i++){
          int tg = mb*128 + wm*64 + mt*16 + quad*4 + i;
          int e  = wn*32 + nt*16 + lc;
          int n = tg >> 10, t = tg & 1023;
          size_t o = ((size_t)(n*NH + h)*SEQ + t)*HD + e;
          float vq = aq[mt][nt][i];
          bf16 hq = __float2bfloat16(vq);
          Qhi[o] = hq;
          Qlo[o] = __float2bfloat16(vq - __bfloat162float(hq));
          float vk = ak[mt][nt][i];
          bf16 hk = __float2bfloat16(vk);
          Khi[o] = hk;
          Klo[o] = __float2bfloat16(vk - __bfloat162float(hk));
        }
      }
    }
  } else {
    const bf16* Av = WvT + (size_t)h*HD*DM;
    f32x4 acc[2][4] = {};
    bf16x8 pa0, pb0, pb1;
    auto ldchunk = [&](int kc){
      size_t col = (size_t)kc*32 + sc;
      pa0 = ld8(Av + (size_t)sr*DM + col);
      pb0 = ld8(xh + (size_t)(mb*128 + sr)*DM + col);
      pb1 = ld8(xh + (size_t)(mb*128 + sr + 64)*DM + col);
    };
    ldchunk(0);
    for (int kc = 0; kc < DM/32; kc++){
      *(bf16x8*)&sB[0][sr*LDA + sc] = pa0;
      *(bf16x8*)&sA[0][sr*LDA + sc] = pb0;
      *(bf16x8*)&sA[0][(sr+64)*LDA + sc] = pb1;
      __syncthreads();
      if (kc < DM/32 - 1) ldchunk(kc + 1);
      bf16x8 bt[4];
      #pragma unroll
      for (int nt = 0; nt < 4; nt++)
        bt[nt] = *(const bf16x8*)&sA[0][(wn*64 + nt*16 + lc)*LDA + quad*8];
      #pragma unroll
      for (int mt = 0; mt < 2; mt++){
        bf16x8 a = *(const bf16x8*)&sB[0][(wm*32 + mt*16 + lc)*LDA + quad*8];
        #pragma unroll
        for (int nt = 0; nt < 4; nt++)
          acc[mt][nt] = mfma16(a, bt[nt], acc[mt][nt]);
      }
      __syncthreads();
    }
    #pragma unroll
    for (int mt = 0; mt < 2; mt++){
      #pragma unroll
      for (int nt = 0; nt < 4; nt++){
        #pragma unroll
        for (int i = 0; i < 4; i++){
          int e  = wm*32 + mt*16 + quad*4 + i;
          int tg = mb*128 + wn*64 + nt*16 + lc;
          int n = tg >> 10, t = tg & 1023;
          Vt[((size_t)(n*NH + h)*HD + e)*SEQ + t] = __float2bfloat16(acc[mt][nt][i]);
        }
      }
    }
  }
}

// ---------------- fused scores + softmax + attn-stream + PV ----------------
__global__ __launch_bounds__(256) void kattn_pv(const bf16* __restrict__ Qhi, const bf16* __restrict__ Qlo,
                                                const bf16* __restrict__ Khi, const bf16* __restrict__ Klo,
                                                const bf16* __restrict__ Vt,
                                                float* __restrict__ attn, bf16* __restrict__ O){
  __shared__ bf16 sP[16][SEQ + 8];
  __shared__ float msh[4][16], lsh[4][16];
  const int tid = threadIdx.x;
  const int lane = tid & 63, w = tid >> 6;
  const int quad = lane >> 4, lc = lane & 15;
  const int t0 = blockIdx.x * 16;
  const int nh = blockIdx.y;
  const size_t base = (size_t)nh * SEQ * HD;
  const float NEGINF = -__builtin_inff();

  f32x4 acc[16] = {};
  const bf16* qh = Qhi + base + (size_t)(t0 + lc)*HD;
  const bf16* ql = Qlo + base + (size_t)(t0 + lc)*HD;
  bf16x8 ah0 = ld8(qh + quad*8), ah1 = ld8(qh + 32 + quad*8);
  bf16x8 al0 = ld8(ql + quad*8), al1 = ld8(ql + 32 + quad*8);
  const int tmax = t0 + 15;
  const int cbase = w*256;

  // software-pipelined QK over 16 col-tiles (double-buffered K fragments)
  bf16x8 kb[2][4];
  auto loadK = [&](int tl, int b){
    const bf16* kh = Khi + base + (size_t)(cbase + tl*16 + lc)*HD;
    const bf16* kl = Klo + base + (size_t)(cbase + tl*16 + lc)*HD;
    kb[b][0] = ld8(kh + quad*8);  kb[b][1] = ld8(kh + 32 + quad*8);
    kb[b][2] = ld8(kl + quad*8);  kb[b][3] = ld8(kl + 32 + quad*8);
  };
  if (cbase <= tmax) loadK(0, 0);
  #pragma unroll
  for (int tl = 0; tl < 16; tl++){
    if (cbase + tl*16 <= tmax){
      if (tl < 15 && cbase + (tl+1)*16 <= tmax) loadK(tl+1, (tl+1)&1);
      const int b = tl & 1;
      acc[tl] = mfma16(ah0, kb[b][0], acc[tl]);
      acc[tl] = mfma16(ah1, kb[b][1], acc[tl]);
      acc[tl] = mfma16(ah0, kb[b][2], acc[tl]);
      acc[tl] = mfma16(ah1, kb[b][3], acc[tl]);
      acc[tl] = mfma16(al0, kb[b][0], acc[tl]);
      acc[tl] = mfma16(al1, kb[b][1], acc[tl]);
    }
  }

  float mx[4] = {NEGINF, NEGINF, NEGINF, NEGINF};
  #pragma unroll
  for (int tl = 0; tl < 16; tl++){
    int col = cbase + tl*16 + lc;
    #pragma unroll
    for (int i = 0; i < 4; i++){
      int r = t0 + quad*4 + i;
      float v = acc[tl][i];
      if (col <= r && v != 0.0f) mx[i] = fmaxf(mx[i], v);
    }
  }
  #pragma unroll
  for (int off = 8; off; off >>= 1){
    #pragma unroll
    for (int i = 0; i < 4; i++) mx[i] = fmaxf(mx[i], __shfl_xor(mx[i], off, 16));
  }
  float sm[4] = {0.f, 0.f, 0.f, 0.f};
  #pragma unroll
  for (int tl = 0; tl < 16; tl++){
    int col = cbase + tl*16 + lc;
    #pragma unroll
    for (int i = 0; i < 4; i++){
      int r = t0 + quad*4 + i;
      float v = acc[tl][i];
      float e = (col <= r && v != 0.0f) ? __expf(v - mx[i]) : 0.0f;
      acc[tl][i] = e;
      sm[i] += e;
    }
  }
  #pragma unroll
  for (int off = 8; off; off >>= 1){
    #pragma unroll
    for (int i = 0; i < 4; i++) sm[i] += __shfl_xor(sm[i], off, 16);
  }
  if (lc == 0){
    #pragma unroll
    for (int i = 0; i < 4; i++){ msh[w][quad*4 + i] = mx[i]; lsh[w][quad*4 + i] = sm[i]; }
  }
  __syncthreads();
  float scale[4];
  #pragma unroll
  for (int i = 0; i < 4; i++){
    int rl = quad*4 + i;
    float M = fmaxf(fmaxf(msh[0][rl], msh[1][rl]), fmaxf(msh[2][rl], msh[3][rl]));
    float L = 0.f;
    #pragma unroll
    for (int w2 = 0; w2 < 4; w2++) L += lsh[w2][rl] * __expf(msh[w2][rl] - M);
    scale[i] = __expf(mx[i] - M) / L;
  }
  // stage P (bf16) to LDS only
  #pragma unroll
  for (int tl = 0; tl < 16; tl++){
    int col = cbase + tl*16 + lc;
    #pragma unroll
    for (int i = 0; i < 4; i++){
      sP[quad*4 + i][col] = __float2bfloat16(acc[tl][i] * scale[i]);
    }
  }
  __syncthreads();

  // stream attn out: 16 rows, each row written as wave-contiguous float4 stores
  #pragma unroll
  for (int r = 0; r < 16; r++){
    const unsigned* sPu = (const unsigned*)&sP[r][0];
    uint2 v = *(const uint2*)(sPu + tid*2);
    f32x4 f;
    f[0] = __uint_as_float(v.x << 16);
    f[1] = __uint_as_float(v.x & 0xFFFF0000u);
    f[2] = __uint_as_float(v.y << 16);
    f[3] = __uint_as_float(v.y & 0xFFFF0000u);
    *(f32x4*)(attn + ((size_t)nh*SEQ + t0 + r)*SEQ + tid*4) = f;
  }

  // PV: wave w -> output cols [w*16, w*16+16)
  f32x4 oacc = {};
  const bf16* Vb = Vt + ((size_t)nh*HD + w*16 + lc)*SEQ;
  const int kend = t0 + 16;
  for (int s0 = 0; s0 < kend; s0 += 32){
    bf16x8 a = *(const bf16x8*)&sP[lc][s0 + quad*8];
    bf16x8 b = ld8(Vb + s0 + quad*8);
    oacc = mfma16(a, b, oacc);
  }
  const int n = nh / NH, h = nh % NH;
  #pragma unroll
  for (int i = 0; i < 4; i++){
    O[((size_t)n*SEQ + t0 + quad*4 + i)*DM + h*HD + w*16 + lc] = __float2bfloat16(oacc[i]);
  }
}

// ---------------- out = O @ Wo + bo  (M-tile 32 -> 128 blocks) ----------------
__global__ __launch_bounds__(256) void kout(const bf16* __restrict__ O, const bf16* __restrict__ WoT,
                                            const float* __restrict__ bo, float* __restrict__ out){
  const int lane = threadIdx.x & 63, w = threadIdx.x >> 6;
  const int quad = lane >> 4, lc = lane & 15;
  const int wm = w & 1, wn = w >> 1;
  const int g = blockIdx.x * 32;
  const int n = g >> 10, tb = g & 1023;
  const bf16* Or = O + ((size_t)n*SEQ + tb + wm*16 + lc)*DM;
  f32x4 acc[2] = {};
  for (int k0 = 0; k0 < DM; k0 += 32){
    bf16x8 a = ld8(Or + k0 + quad*8);
    #pragma unroll
    for (int nt = 0; nt < 2; nt++){
      bf16x8 b = ld8(WoT + (size_t)(wn*32 + nt*16 + lc)*DM + k0 + quad*8);
      acc[nt] = mfma16(a, b, acc[nt]);
    }
  }
  #pragma unroll
  for (int nt = 0; nt < 2; nt++){
    float bias = bo[wn*32 + nt*16 + lc];
    #pragma unroll
    for (int i = 0; i < 4; i++){
      out[((size_t)n*SEQ + tb + wm*16 + quad*4 + i)*HD + wn*32 + nt*16 + lc] = acc[nt][i] + bias;
    }
  }
}

extern "C" void kernel_launch(void* const* d_in, const int* in_sizes, int n_in,
                              void* d_out, int out_size, void* d_ws, size_t ws_size,
                              hipStream_t stream){
  const float* x  = (const float*)d_in[0];
  const float* Wq = (const float*)d_in[1];
  const float* Wk = (const float*)d_in[2];
  const float* Wv = (const float*)d_in[3];
  const float* Wo = (const float*)d_in[4];
  const float* bo = (const float*)d_in[5];

  float* out  = (float*)d_out;
  float* attn = out + (size_t)NB*SEQ*HD;

  constexpr size_t SZ_WT  = (size_t)NH*HD*DM;
  constexpr size_t SZ_WOT = (size_t)HD*DM;
  constexpr size_t SZ_Q   = (size_t)NB*NH*SEQ*HD;
  bf16* b = (bf16*)d_ws;
  bf16* WqTh = b;  b += SZ_WT;
  bf16* WqTl = b;  b += SZ_WT;
  bf16* WkTh = b;  b += SZ_WT;
  bf16* WkTl = b;  b += SZ_WT;
  bf16* WvT  = b;  b += SZ_WT;
  bf16* WoT  = b;  b += SZ_WOT;
  bf16* xh   = b;  b += SZ_Q;
  bf16* xl   = b;  b += SZ_Q;
  bf16* Qhi  = b;  b += SZ_Q;
  bf16* Qlo  = b;  b += SZ_Q;
  bf16* Khi  = b;  b += SZ_Q;
  bf16* Klo  = b;  b += SZ_Q;
  bf16* Vt   = b;  b += SZ_Q;
  bf16* O    = xh;   // alias: xh dead after kproj

  wprep<<<dim3(12, 37), 256, 0, stream>>>(Wq, Wk, Wv, Wo, WqTh, WqTl, WkTh, WkTl, WvT, WoT);
  xprep<<<dim3((int)(SZ_Q/(256*8))), 256, 0, stream>>>(x, xh, xl);
  kproj<<<dim3(NB*SEQ/128, NH, 2), 256, 0, stream>>>(xh, xl, WqTh, WqTl, WkTh, WkTl, WvT,
                                                     Qhi, Qlo, Khi, Klo, Vt);
  kattn_pv<<<dim3(SEQ/16, NB*NH), 256, 0, stream>>>(Qhi, Qlo, Khi, Klo, Vt, attn, O);
  kout<<<dim3(NB*SEQ/32), 256, 0, stream>>>(O, WoT, bo, out);
}